// Round 6
// baseline (319.446 us; speedup 1.0000x reference)
//
#include <hip/hip_runtime.h>

#define N_DIM 512
#define M_DIM 512
#define NQUAD 128           // 512 rows as 128 row-quads
#define TSTEPS 191          // 128 quads + 63 lane skew
#define DEPTH 4             // LDS ring depth (quads)
#define SLOT_BYTES 8192     // 8 chunks x (64 lanes x 16B)
#define RING_BYTES (DEPTH * SLOT_BYTES)

#define AS1 __attribute__((address_space(1)))
#define AS3 __attribute__((address_space(3)))

// Soft-DTW forward DP, exp-domain banded wavefront, 4 rows per step.
// One wave per batch; lane l owns columns [8l, 8l+8); step s computes
// row-quad t = s-l (rows 4t..4t+3). E[j] = exp(g - R[i][j]) makes each cell
// one FMA; exp(-d) and the output logs are off the serial chain.
__global__ __launch_bounds__(64, 1) void softdtw_kernel(const float* __restrict__ D,
                                                        float* __restrict__ R) {
    const int b  = blockIdx.x;
    const int l  = threadIdx.x;      // lane 0..63
    const int c0 = l << 3;

    const float* __restrict__ Db = D + (size_t)b * N_DIM * M_DIM;
    float*       __restrict__ Rb = R + (size_t)b * N_DIM * M_DIM;

    __shared__ char ring[RING_BYTES] __attribute__((aligned(16)));
    const unsigned ring_base = (unsigned)(size_t)(AS3 char*)ring;

    // DMA the 4 rows of quad (sigma - l) into slot sigma % DEPTH.
    auto DMA8 = [&](int sigma) {
        const int tF = sigma - l;
        const unsigned wo = (unsigned)(sigma & (DEPTH - 1)) * SLOT_BYTES;
        #pragma unroll
        for (int k = 0; k < 4; ++k) {
            const int r = min(max(4 * tF + k, 0), N_DIM - 1);
            const float* gp = Db + (size_t)r * M_DIM + c0;
            __builtin_amdgcn_global_load_lds((const AS1 void*)gp,
                                             (AS3 void*)(ring + wo + (2 * k) * 1024), 16, 0, 0);
            __builtin_amdgcn_global_load_lds((const AS1 void*)(gp + 4),
                                             (AS3 void*)(ring + wo + (2 * k + 1) * 1024), 16, 0, 0);
        }
    };

    // ---- persistent state ----
    float Ep[8];                      // E of row 4t-1 (prev quad row D), frame F
    #pragma unroll
    for (int k = 0; k < 8; ++k) Ep[k] = 0.0f;
    float F = 0.0f, G = 0.0f, fQ = 0.0f;
    float expA7 = 0.0f, expB7 = 0.0f, expC7 = 0.0f, expD7 = 0.0f;
    float E7hD = 0.0f, Fh = 0.0f;     // neighbor's (expD7, F) one step ago
    float endA[8], endB[8], endC[8], endD[8];

    // ---- prologue: quad 0 via direct loads; DMA slots 1..3 ----
    {
        auto ld = [&](int k, float* dst) {
            const int r = min(max(-4 * l + k, 0), N_DIM - 1);
            const float4 a = *(const float4*)(Db + (size_t)r * M_DIM + c0);
            const float4 c = *(const float4*)(Db + (size_t)r * M_DIM + c0 + 4);
            dst[0] = __expf(-a.x); dst[1] = __expf(-a.y);
            dst[2] = __expf(-a.z); dst[3] = __expf(-a.w);
            dst[4] = __expf(-c.x); dst[5] = __expf(-c.y);
            dst[6] = __expf(-c.z); dst[7] = __expf(-c.w);
        };
        ld(0, endA); ld(1, endB); ld(2, endC); ld(3, endD);
    }
    DMA8(1); DMA8(2); DMA8(3);
    asm volatile("s_waitcnt vmcnt(16)" ::: "memory");   // slot 1 complete

    auto rowfma = [&](const float* endv, float eLeft, const float* Q, float* E) {
        float e = eLeft;
        #pragma unroll
        for (int c = 0; c < 8; ++c) {
            e = __builtin_fmaf(endv[c], e, endv[c] * Q[c]);
            E[c] = e;
        }
    };

    for (int s = 0; s < TSTEPS; ++s) {
        // (1) prefetch DMA for step s+DEPTH
        DMA8(s + DEPTH);
        // (2) counted drain: read slot's 8 DMAs are >= 40 vmem-ops old
        asm volatile("s_waitcnt vmcnt(32)" ::: "memory");

        // (3) issue ds_read of next step's D (latency hides under compute)
        const unsigned raddr = ring_base
                             + (unsigned)((s + 1) & (DEPTH - 1)) * SLOT_BYTES
                             + (unsigned)l * 16u;
        float4 q0, q1, q2, q3, q4, q5, q6, q7;
        asm volatile("ds_read_b128 %0, %8 offset:0\n\t"
                     "ds_read_b128 %1, %8 offset:1024\n\t"
                     "ds_read_b128 %2, %8 offset:2048\n\t"
                     "ds_read_b128 %3, %8 offset:3072\n\t"
                     "ds_read_b128 %4, %8 offset:4096\n\t"
                     "ds_read_b128 %5, %8 offset:5120\n\t"
                     "ds_read_b128 %6, %8 offset:6144\n\t"
                     "ds_read_b128 %7, %8 offset:7168"
                     : "=&v"(q0), "=&v"(q1), "=&v"(q2), "=&v"(q3),
                       "=&v"(q4), "=&v"(q5), "=&v"(q6), "=&v"(q7)
                     : "v"(raddr));

        // (4) boundary from lane l-1 (end of its step s-1)
        float E7sA = __shfl_up(expA7, 1);
        float E7sB = __shfl_up(expB7, 1);
        float E7sC = __shfl_up(expC7, 1);
        float E7sD = __shfl_up(expD7, 1);
        float Fs   = __shfl_up(F, 1);

        // (5) compute quad t = s - l
        const int t = s - l;
        if (t >= 0 && t < NQUAD) {
            const int i0 = t << 2;
            float g, factor, eLeftA, eDiagA0;
            if (t == 0) {
                if (l == 0) { g = 0.0f; factor = 0.0f; eLeftA = 0.0f; eDiagA0 = 1.0f; }
                else {
                    g       = Fs - __logf(E7sA);   // adopt incoming boundary value
                    factor  = 1.0f / E7sA;         // = exp(g - Fs)
                    eLeftA  = 1.0f;
                    eDiagA0 = 0.0f;                // row -1 is BIG
                }
                fQ = 0.0f;                          // prev row all BIG
            } else {
                g       = G;
                factor  = __expf(g - Fs);
                eLeftA  = (l == 0) ? 0.0f : E7sA * factor;
                eDiagA0 = (l == 0) ? 0.0f : E7hD * __expf(g - Fh);
            }

            float QA[8];
            QA[0] = eDiagA0 + fQ * Ep[0];
            #pragma unroll
            for (int c = 1; c < 8; ++c) QA[c] = fQ * (Ep[c - 1] + Ep[c]);
            float EA[8];
            rowfma(endA, eLeftA, QA, EA);

            float QB[8];
            QB[0] = ((l == 0) ? 0.0f : E7sA * factor) + EA[0];
            #pragma unroll
            for (int c = 1; c < 8; ++c) QB[c] = EA[c - 1] + EA[c];
            float EB[8];
            rowfma(endB, (l == 0) ? 0.0f : E7sB * factor, QB, EB);

            float QC[8];
            QC[0] = ((l == 0) ? 0.0f : E7sB * factor) + EB[0];
            #pragma unroll
            for (int c = 1; c < 8; ++c) QC[c] = EB[c - 1] + EB[c];
            float EC[8];
            rowfma(endC, (l == 0) ? 0.0f : E7sC * factor, QC, EC);

            float QD[8];
            QD[0] = ((l == 0) ? 0.0f : E7sC * factor) + EC[0];
            #pragma unroll
            for (int c = 1; c < 8; ++c) QD[c] = EC[c - 1] + EC[c];
            float ED[8];
            rowfma(endD, (l == 0) ? 0.0f : E7sD * factor, QD, ED);

            // recover r = g - log(E), store 4 rows (off the serial chain)
            float oA[8], oB[8], oC[8], oD[8];
            #pragma unroll
            for (int c = 0; c < 8; ++c) oA[c] = g - __logf(EA[c]);
            #pragma unroll
            for (int c = 0; c < 8; ++c) oB[c] = g - __logf(EB[c]);
            #pragma unroll
            for (int c = 0; c < 8; ++c) oC[c] = g - __logf(EC[c]);
            #pragma unroll
            for (int c = 0; c < 8; ++c) oD[c] = g - __logf(ED[c]);
            float4* rA = (float4*)(Rb + (size_t)(i0 + 0) * M_DIM + c0);
            rA[0] = make_float4(oA[0], oA[1], oA[2], oA[3]);
            rA[1] = make_float4(oA[4], oA[5], oA[6], oA[7]);
            float4* rB = (float4*)(Rb + (size_t)(i0 + 1) * M_DIM + c0);
            rB[0] = make_float4(oB[0], oB[1], oB[2], oB[3]);
            rB[1] = make_float4(oB[4], oB[5], oB[6], oB[7]);
            float4* rC = (float4*)(Rb + (size_t)(i0 + 2) * M_DIM + c0);
            rC[0] = make_float4(oC[0], oC[1], oC[2], oC[3]);
            rC[1] = make_float4(oC[4], oC[5], oC[6], oC[7]);
            float4* rD = (float4*)(Rb + (size_t)(i0 + 3) * M_DIM + c0);
            rD[0] = make_float4(oD[0], oD[1], oD[2], oD[3]);
            rD[1] = make_float4(oD[4], oD[5], oD[6], oD[7]);

            // next-step frame: g_next = R[4t+3][8l]  =>  fQ = 1/ED[0]
            G  = oD[0];
            fQ = 1.0f / ED[0];
            F  = g;
            #pragma unroll
            for (int c = 0; c < 8; ++c) Ep[c] = ED[c];
            expA7 = EA[7]; expB7 = EB[7]; expC7 = EC[7]; expD7 = ED[7];
        }

        // (6) history update (all lanes)
        E7hD = E7sD;
        Fh   = Fs;

        // (7) drain ds_reads, convert to end[] for the next step (rule 18)
        asm volatile("s_waitcnt lgkmcnt(0)" ::: "memory");
        __builtin_amdgcn_sched_barrier(0);
        endA[0] = __expf(-q0.x); endA[1] = __expf(-q0.y);
        endA[2] = __expf(-q0.z); endA[3] = __expf(-q0.w);
        endA[4] = __expf(-q1.x); endA[5] = __expf(-q1.y);
        endA[6] = __expf(-q1.z); endA[7] = __expf(-q1.w);
        endB[0] = __expf(-q2.x); endB[1] = __expf(-q2.y);
        endB[2] = __expf(-q2.z); endB[3] = __expf(-q2.w);
        endB[4] = __expf(-q3.x); endB[5] = __expf(-q3.y);
        endB[6] = __expf(-q3.z); endB[7] = __expf(-q3.w);
        endC[0] = __expf(-q4.x); endC[1] = __expf(-q4.y);
        endC[2] = __expf(-q4.z); endC[3] = __expf(-q4.w);
        endC[4] = __expf(-q5.x); endC[5] = __expf(-q5.y);
        endC[6] = __expf(-q5.z); endC[7] = __expf(-q5.w);
        endD[0] = __expf(-q6.x); endD[1] = __expf(-q6.y);
        endD[2] = __expf(-q6.z); endD[3] = __expf(-q6.w);
        endD[4] = __expf(-q7.x); endD[5] = __expf(-q7.y);
        endD[6] = __expf(-q7.z); endD[7] = __expf(-q7.w);
    }
}

extern "C" void kernel_launch(void* const* d_in, const int* in_sizes, int n_in,
                              void* d_out, int out_size, void* d_ws, size_t ws_size,
                              hipStream_t stream) {
    const float* x = (const float*)d_in[0];
    float* out     = (float*)d_out;
    const int B    = in_sizes[0] / (N_DIM * M_DIM);
    softdtw_kernel<<<dim3(B), dim3(64), 0, stream>>>(x, out);
}

// Round 7
// 146.619 us; speedup vs baseline: 2.1787x; 2.1787x over previous
//
#include <hip/hip_runtime.h>

#define N_DIM 512
#define M_DIM 512
#define NQUAD 128
#define TSTEPS 192          // even (ping-pong); 128 quads + 63 skew, padded
#define DEPTH 4
#define SLOT_BYTES 8192
#define RING_BYTES (DEPTH * SLOT_BYTES)
#define BSTRIDE (N_DIM * M_DIM)
#define GSTRIDE (NQUAD * 64)

#define AS1 __attribute__((address_space(1)))
#define AS3 __attribute__((address_space(3)))

// -------- pass 1: Dexp = exp(-D), all CUs, memory-bound --------
__global__ __launch_bounds__(256) void exp_pre(const float4* __restrict__ D4,
                                               float4* __restrict__ E4, int n4) {
    int i = blockIdx.x * blockDim.x + threadIdx.x;
    const int stride = gridDim.x * blockDim.x;
    for (; i < n4; i += stride) {
        const float4 v = D4[i];
        E4[i] = make_float4(__expf(-v.x), __expf(-v.y), __expf(-v.z), __expf(-v.w));
    }
}

// -------- pass 3: R = g - log(E), in place on d_out --------
__global__ __launch_bounds__(256) void log_post(float4* __restrict__ E4,
                                                const float* __restrict__ gm, int n4) {
    int i = blockIdx.x * blockDim.x + threadIdx.x;
    const int stride = gridDim.x * blockDim.x;
    for (; i < n4; i += stride) {
        const int b   = i >> 16;            // 65536 float4 per batch
        const int rem = i & 65535;
        const int row = rem >> 7;           // 128 float4 per row
        const int c4  = rem & 127;
        const float g = gm[(b << 13) + ((row >> 2) << 6) + (c4 >> 1)];
        const float4 v = E4[i];
        E4[i] = make_float4(g - __logf(v.x), g - __logf(v.y),
                            g - __logf(v.z), g - __logf(v.w));
    }
}

// -------- pass 2: exp-domain banded DP wave (4 rows/step) --------
// Lane l owns columns [8l,8l+8); step s computes row-quad t = s-l.
// Each cell: E = end*(E_left + E_diag + E_up) -> add,add... here kept as
// Q-add + mul + fma. Writes E to Eout and frame g to gmap; NO per-cell trans.
template<bool PRE>
__global__ __launch_bounds__(64, 1) void softdtw_dp(const float* __restrict__ Dsrc,
                                                    float* __restrict__ Eout,
                                                    float* __restrict__ gmap) {
    const int b  = blockIdx.x;
    const int l  = threadIdx.x;
    const int c0 = l << 3;

    const float* __restrict__ Db = Dsrc + (size_t)b * BSTRIDE;  // exp(-D) if PRE
    float*       __restrict__ Rb = Eout + (size_t)b * BSTRIDE;
    float*       __restrict__ gm = gmap + (size_t)b * GSTRIDE;

    __shared__ char ring[RING_BYTES] __attribute__((aligned(16)));
    const unsigned ring_base = (unsigned)(size_t)(AS3 char*)ring;

    auto DMA8 = [&](int sigma) {
        const int tF = sigma - l;
        const unsigned wo = (unsigned)(sigma & (DEPTH - 1)) * SLOT_BYTES;
        #pragma unroll
        for (int k = 0; k < 4; ++k) {
            const int r = min(max(4 * tF + k, 0), N_DIM - 1);
            const float* gp = Db + (size_t)r * M_DIM + c0;
            __builtin_amdgcn_global_load_lds((const AS1 void*)gp,
                                             (AS3 void*)(ring + wo + (2 * k) * 1024), 16, 0, 0);
            __builtin_amdgcn_global_load_lds((const AS1 void*)(gp + 4),
                                             (AS3 void*)(ring + wo + (2 * k + 1) * 1024), 16, 0, 0);
        }
    };

    auto EV = [&](float v) -> float { return PRE ? v : __expf(-v); };

    // persistent state
    float Ep[8];
    #pragma unroll
    for (int k = 0; k < 8; ++k) Ep[k] = 0.0f;
    float F = 0.0f, G = 0.0f, fQ = 0.0f;
    float expA7 = 0.0f, expB7 = 0.0f, expC7 = 0.0f, expD7 = 0.0f;
    float E7hD = 0.0f, Fh = 0.0f;

    float4 P[8], Nx[8];
    // prologue: quad 0 (raw values; EV converts at consume) + fill slots 1..3
    #pragma unroll
    for (int row = 0; row < 4; ++row) {
        const int r = min(max(-4 * l + row, 0), N_DIM - 1);
        P[2 * row]     = *(const float4*)(Db + (size_t)r * M_DIM + c0);
        P[2 * row + 1] = *(const float4*)(Db + (size_t)r * M_DIM + c0 + 4);
    }
    DMA8(1); DMA8(2); DMA8(3);
    asm volatile("s_waitcnt vmcnt(0)" ::: "memory");   // slots 1..3 resident

    auto rowfma = [&](const float* endv, float eLeft, const float* Q, float* E) {
        float e = eLeft;
        #pragma unroll
        for (int c = 0; c < 8; ++c) {
            e = __builtin_fmaf(endv[c], e, endv[c] * Q[c]);
            E[c] = e;
        }
    };

    auto step = [&](int s, float4 (&cur)[8], float4 (&nxt)[8]) {
        DMA8(s + DEPTH);
        // stores count in vmcnt too: ops newer than slot-(s+1)'s batch are
        // st(s-3)9 + D(s+2)8 + st(s-2)9 + D(s+3)8 + st(s-1)9 + D(s+4)8 = 51.
        asm volatile("s_waitcnt vmcnt(51)" ::: "memory");

        // boundary from lane l-1 (end of its step s-1)
        const float E7sA = __shfl_up(expA7, 1);
        const float E7sB = __shfl_up(expB7, 1);
        const float E7sC = __shfl_up(expC7, 1);
        const float E7sD = __shfl_up(expD7, 1);
        const float Fs   = __shfl_up(F, 1);

        // issue ds_read of next step's quad (completes under compute)
        const unsigned raddr = ring_base
                             + (unsigned)((s + 1) & (DEPTH - 1)) * SLOT_BYTES
                             + (unsigned)l * 16u;
        asm volatile("ds_read_b128 %0, %8 offset:0\n\t"
                     "ds_read_b128 %1, %8 offset:1024\n\t"
                     "ds_read_b128 %2, %8 offset:2048\n\t"
                     "ds_read_b128 %3, %8 offset:3072\n\t"
                     "ds_read_b128 %4, %8 offset:4096\n\t"
                     "ds_read_b128 %5, %8 offset:5120\n\t"
                     "ds_read_b128 %6, %8 offset:6144\n\t"
                     "ds_read_b128 %7, %8 offset:7168"
                     : "=&v"(nxt[0]), "=&v"(nxt[1]), "=&v"(nxt[2]), "=&v"(nxt[3]),
                       "=&v"(nxt[4]), "=&v"(nxt[5]), "=&v"(nxt[6]), "=&v"(nxt[7])
                     : "v"(raddr));

        const int t = s - l;
        if (t >= 0 && t < NQUAD) {
            const float endA[8] = {EV(cur[0].x), EV(cur[0].y), EV(cur[0].z), EV(cur[0].w),
                                   EV(cur[1].x), EV(cur[1].y), EV(cur[1].z), EV(cur[1].w)};
            const float endB[8] = {EV(cur[2].x), EV(cur[2].y), EV(cur[2].z), EV(cur[2].w),
                                   EV(cur[3].x), EV(cur[3].y), EV(cur[3].z), EV(cur[3].w)};
            const float endC[8] = {EV(cur[4].x), EV(cur[4].y), EV(cur[4].z), EV(cur[4].w),
                                   EV(cur[5].x), EV(cur[5].y), EV(cur[5].z), EV(cur[5].w)};
            const float endD[8] = {EV(cur[6].x), EV(cur[6].y), EV(cur[6].z), EV(cur[6].w),
                                   EV(cur[7].x), EV(cur[7].y), EV(cur[7].z), EV(cur[7].w)};

            const int i0 = t << 2;
            float g, factor, eLeftA, eDiagA0;
            if (t == 0) {
                if (l == 0) { g = 0.0f; factor = 0.0f; eLeftA = 0.0f; eDiagA0 = 1.0f; }
                else {
                    g       = Fs - __logf(E7sA);   // adopt incoming boundary value
                    factor  = 1.0f / E7sA;
                    eLeftA  = 1.0f;
                    eDiagA0 = 0.0f;
                }
                fQ = 0.0f;
            } else {
                g       = G;
                factor  = __expf(g - Fs);
                eLeftA  = (l == 0) ? 0.0f : E7sA * factor;
                eDiagA0 = (l == 0) ? 0.0f : E7hD * __expf(g - Fh);
            }

            float QA[8];
            QA[0] = eDiagA0 + fQ * Ep[0];
            #pragma unroll
            for (int c = 1; c < 8; ++c) QA[c] = fQ * (Ep[c - 1] + Ep[c]);
            float EA[8];
            rowfma(endA, eLeftA, QA, EA);

            float QB[8];
            QB[0] = ((l == 0) ? 0.0f : E7sA * factor) + EA[0];
            #pragma unroll
            for (int c = 1; c < 8; ++c) QB[c] = EA[c - 1] + EA[c];
            float EB[8];
            rowfma(endB, (l == 0) ? 0.0f : E7sB * factor, QB, EB);

            float QC[8];
            QC[0] = ((l == 0) ? 0.0f : E7sB * factor) + EB[0];
            #pragma unroll
            for (int c = 1; c < 8; ++c) QC[c] = EB[c - 1] + EB[c];
            float EC[8];
            rowfma(endC, (l == 0) ? 0.0f : E7sC * factor, QC, EC);

            float QD[8];
            QD[0] = ((l == 0) ? 0.0f : E7sC * factor) + EC[0];
            #pragma unroll
            for (int c = 1; c < 8; ++c) QD[c] = EC[c - 1] + EC[c];
            float ED[8];
            rowfma(endD, (l == 0) ? 0.0f : E7sD * factor, QD, ED);

            // store E directly (post-pass converts); frame to gmap
            float4* rA = (float4*)(Rb + (size_t)(i0 + 0) * M_DIM + c0);
            rA[0] = make_float4(EA[0], EA[1], EA[2], EA[3]);
            rA[1] = make_float4(EA[4], EA[5], EA[6], EA[7]);
            float4* rB = (float4*)(Rb + (size_t)(i0 + 1) * M_DIM + c0);
            rB[0] = make_float4(EB[0], EB[1], EB[2], EB[3]);
            rB[1] = make_float4(EB[4], EB[5], EB[6], EB[7]);
            float4* rC = (float4*)(Rb + (size_t)(i0 + 2) * M_DIM + c0);
            rC[0] = make_float4(EC[0], EC[1], EC[2], EC[3]);
            rC[1] = make_float4(EC[4], EC[5], EC[6], EC[7]);
            float4* rD = (float4*)(Rb + (size_t)(i0 + 3) * M_DIM + c0);
            rD[0] = make_float4(ED[0], ED[1], ED[2], ED[3]);
            rD[1] = make_float4(ED[4], ED[5], ED[6], ED[7]);
            gm[(t << 6) + l] = g;

            // frame update: g_next = g - log(ED[0]); fQ = 1/ED[0]
            const float ed0 = ED[0];
            float rcp;
            asm("v_rcp_f32 %0, %1" : "=v"(rcp) : "v"(ed0));
            G  = g - __logf(ed0);
            fQ = rcp;
            F  = g;
            #pragma unroll
            for (int c = 0; c < 8; ++c) Ep[c] = ED[c];
            expA7 = EA[7]; expB7 = EB[7]; expC7 = EC[7]; expD7 = ED[7];
        }

        E7hD = E7sD;
        Fh   = Fs;

        // finalize next quad's ds_reads before they become 'cur' (rule 18)
        asm volatile("s_waitcnt lgkmcnt(0)" ::: "memory");
        __builtin_amdgcn_sched_barrier(0);
    };

    for (int s = 0; s < TSTEPS; s += 2) {
        step(s,     P,  Nx);
        step(s + 1, Nx, P);
    }
}

extern "C" void kernel_launch(void* const* d_in, const int* in_sizes, int n_in,
                              void* d_out, int out_size, void* d_ws, size_t ws_size,
                              hipStream_t stream) {
    const float* x = (const float*)d_in[0];
    float* out     = (float*)d_out;
    const int B    = in_sizes[0] / BSTRIDE;
    const int n4   = (B * BSTRIDE) / 4;
    const size_t DEXP_BYTES = (size_t)B * BSTRIDE * sizeof(float);
    const size_t GMAP_BYTES = (size_t)B * GSTRIDE * sizeof(float);

    if (ws_size >= DEXP_BYTES + GMAP_BYTES) {
        float* dexp = (float*)d_ws;
        float* gm   = (float*)((char*)d_ws + DEXP_BYTES);
        exp_pre<<<dim3(2048), dim3(256), 0, stream>>>((const float4*)x, (float4*)dexp, n4);
        softdtw_dp<true><<<dim3(B), dim3(64), 0, stream>>>(dexp, out, gm);
        log_post<<<dim3(2048), dim3(256), 0, stream>>>((float4*)out, gm, n4);
    } else {
        float* gm = (float*)d_ws;                    // needs only 1 MB
        softdtw_dp<false><<<dim3(B), dim3(64), 0, stream>>>(x, out, gm);
        log_post<<<dim3(2048), dim3(256), 0, stream>>>((float4*)out, gm, n4);
    }
}

// Round 8
// 137.402 us; speedup vs baseline: 2.3249x; 1.0671x over previous
//
#include <hip/hip_runtime.h>

#define N_DIM 512
#define M_DIM 512
#define NQUAD 128
#define TSTEPS 192          // even (ping-pong); 128 quads + 63 skew, padded
#define DEPTH 4
#define SLOT_BYTES 8192
#define RING_BYTES (DEPTH * SLOT_BYTES)
#define BSTRIDE (N_DIM * M_DIM)
#define GSTRIDE (NQUAD * 64)
#define LN2F 0.6931471805599453f

#define AS1 __attribute__((address_space(1)))
#define AS3 __attribute__((address_space(3)))

// -------- pass 1: Dexp = exp(-D), all CUs, memory-bound --------
__global__ __launch_bounds__(256) void exp_pre(const float4* __restrict__ D4,
                                               float4* __restrict__ E4, int n4) {
    int i = blockIdx.x * blockDim.x + threadIdx.x;
    const int stride = gridDim.x * blockDim.x;
    for (; i < n4; i += stride) {
        const float4 v = D4[i];
        E4[i] = make_float4(__expf(-v.x), __expf(-v.y), __expf(-v.z), __expf(-v.w));
    }
}

// -------- pass 3: R = g - log(E), in place on d_out --------
__global__ __launch_bounds__(256) void log_post(float4* __restrict__ E4,
                                                const float* __restrict__ gm, int n4) {
    int i = blockIdx.x * blockDim.x + threadIdx.x;
    const int stride = gridDim.x * blockDim.x;
    for (; i < n4; i += stride) {
        const int b   = i >> 16;            // 65536 float4 per batch
        const int rem = i & 65535;
        const int row = rem >> 7;           // 128 float4 per row
        const int c4  = rem & 127;
        const float g = gm[(b << 13) + ((row >> 2) << 6) + (c4 >> 1)];
        const float4 v = E4[i];
        E4[i] = make_float4(g - __logf(v.x), g - __logf(v.y),
                            g - __logf(v.z), g - __logf(v.w));
    }
}

// DPP wave-shift-right-by-1: lane i gets lane i-1's value, lane 0 gets 0.
__device__ inline float shup1(float x) {
    int r = __builtin_amdgcn_update_dpp(0, __float_as_int(x), 0x138, 0xf, 0xf, true);
    return __int_as_float(r);
}
__device__ inline int shup1i(int x) {
    return __builtin_amdgcn_update_dpp(0, x, 0x138, 0xf, 0xf, true);
}
__device__ inline int fr_exp(float x) {
    int e; asm("v_frexp_exp_i32_f32 %0, %1" : "=v"(e) : "v"(x)); return e;
}
__device__ inline float ldx(float x, int k) {
    float r; asm("v_ldexp_f32 %0, %1, %2" : "=v"(r) : "v"(x), "v"(k)); return r;
}

// -------- pass 2: exp-domain banded DP wave, integer pow2 frames --------
// Lane l owns columns [8l,8l+8); step s computes row-quad t = s-l.
// Stored E[j] = exp(-R[i][j]) * 2^K per-lane frame; R = K*ln2 - ln(E).
// Steady-state step has ZERO transcendentals; frame ops are exact
// frexp/ldexp; boundary exchange via 1-cycle DPP wave_shr1.
template<bool PRE>
__global__ __launch_bounds__(64, 1) void softdtw_dp(const float* __restrict__ Dsrc,
                                                    float* __restrict__ Eout,
                                                    float* __restrict__ gmap) {
    const int b  = blockIdx.x;
    const int l  = threadIdx.x;
    const int c0 = l << 3;

    const float* __restrict__ Db = Dsrc + (size_t)b * BSTRIDE;  // exp(-D) if PRE
    float*       __restrict__ Rb = Eout + (size_t)b * BSTRIDE;
    float*       __restrict__ gm = gmap + (size_t)b * GSTRIDE;

    __shared__ char ring[RING_BYTES] __attribute__((aligned(16)));
    const unsigned ring_base = (unsigned)(size_t)(AS3 char*)ring;

    auto DMA8 = [&](int sigma) {
        const int tF = sigma - l;
        const unsigned wo = (unsigned)(sigma & (DEPTH - 1)) * SLOT_BYTES;
        #pragma unroll
        for (int k = 0; k < 4; ++k) {
            const int r = min(max(4 * tF + k, 0), N_DIM - 1);
            const float* gp = Db + (size_t)r * M_DIM + c0;
            __builtin_amdgcn_global_load_lds((const AS1 void*)gp,
                                             (AS3 void*)(ring + wo + (2 * k) * 1024), 16, 0, 0);
            __builtin_amdgcn_global_load_lds((const AS1 void*)(gp + 4),
                                             (AS3 void*)(ring + wo + (2 * k + 1) * 1024), 16, 0, 0);
        }
    };

    auto EV = [&](float v) -> float { return PRE ? v : __expf(-v); };

    // persistent state
    float Ep[8];
    #pragma unroll
    for (int k = 0; k < 8; ++k) Ep[k] = 0.0f;
    float fQ = 0.0f;
    int   KG = 0;          // frame chosen for the upcoming quad
    int   KE = 0;          // frame of exported E7 values (neighbor reads as Ks)
    int   Kh = 0;          // history: neighbor's Ks one step ago
    float expA7 = 0.0f, expB7 = 0.0f, expC7 = 0.0f, expD7 = 0.0f;
    float E7hD = 0.0f;     // history: neighbor's expD7 one step ago

    float4 P[8], Nx[8];
    // prologue: quad 0 direct loads + fill ring slots 1..3
    #pragma unroll
    for (int row = 0; row < 4; ++row) {
        const int r = min(max(-4 * l + row, 0), N_DIM - 1);
        P[2 * row]     = *(const float4*)(Db + (size_t)r * M_DIM + c0);
        P[2 * row + 1] = *(const float4*)(Db + (size_t)r * M_DIM + c0 + 4);
    }
    DMA8(1); DMA8(2); DMA8(3);
    asm volatile("s_waitcnt vmcnt(0)" ::: "memory");

    auto rowfma = [&](const float* endv, float eLeft, const float* Q, float* E) {
        float e = eLeft;
        #pragma unroll
        for (int c = 0; c < 8; ++c) {
            e = __builtin_fmaf(endv[c], e, endv[c] * Q[c]);
            E[c] = e;
        }
    };

    auto step = [&](int s, float4 (&cur)[8], float4 (&nxt)[8]) {
        DMA8(s + DEPTH);
        // vmcnt bookkeeping (stores count too): ops newer than slot-(s+1)'s
        // DMA batch: st(s-3)9 + D(s+2)8 + st(s-2)9 + D(s+3)8 + st(s-1)9 + D(s+4)8 = 51
        asm volatile("s_waitcnt vmcnt(51)" ::: "memory");

        // boundary from lane l-1 via DPP (lane 0 gets 0 = BIG boundary)
        const float E7sA = shup1(expA7);
        const float E7sB = shup1(expB7);
        const float E7sC = shup1(expC7);
        const float E7sD = shup1(expD7);
        const int   Ks   = shup1i(KE);

        // issue ds_read of next step's quad (completes under compute)
        const unsigned raddr = ring_base
                             + (unsigned)((s + 1) & (DEPTH - 1)) * SLOT_BYTES
                             + (unsigned)l * 16u;
        asm volatile("ds_read_b128 %0, %8 offset:0\n\t"
                     "ds_read_b128 %1, %8 offset:1024\n\t"
                     "ds_read_b128 %2, %8 offset:2048\n\t"
                     "ds_read_b128 %3, %8 offset:3072\n\t"
                     "ds_read_b128 %4, %8 offset:4096\n\t"
                     "ds_read_b128 %5, %8 offset:5120\n\t"
                     "ds_read_b128 %6, %8 offset:6144\n\t"
                     "ds_read_b128 %7, %8 offset:7168"
                     : "=&v"(nxt[0]), "=&v"(nxt[1]), "=&v"(nxt[2]), "=&v"(nxt[3]),
                       "=&v"(nxt[4]), "=&v"(nxt[5]), "=&v"(nxt[6]), "=&v"(nxt[7])
                     : "v"(raddr));

        const int t = s - l;
        if (t >= 0 && t < NQUAD) {
            const float endA[8] = {EV(cur[0].x), EV(cur[0].y), EV(cur[0].z), EV(cur[0].w),
                                   EV(cur[1].x), EV(cur[1].y), EV(cur[1].z), EV(cur[1].w)};
            const float endB[8] = {EV(cur[2].x), EV(cur[2].y), EV(cur[2].z), EV(cur[2].w),
                                   EV(cur[3].x), EV(cur[3].y), EV(cur[3].z), EV(cur[3].w)};
            const float endC[8] = {EV(cur[4].x), EV(cur[4].y), EV(cur[4].z), EV(cur[4].w),
                                   EV(cur[5].x), EV(cur[5].y), EV(cur[5].z), EV(cur[5].w)};
            const float endD[8] = {EV(cur[6].x), EV(cur[6].y), EV(cur[6].z), EV(cur[6].w),
                                   EV(cur[7].x), EV(cur[7].y), EV(cur[7].z), EV(cur[7].w)};

            // frame selection (branch-free adoption at t==0)
            const bool is0    = (t == 0);
            const bool origin = is0 && (l == 0);
            int K = is0 ? (Ks - fr_exp(E7sA)) : KG;
            K = origin ? 0 : K;
            const float fq = is0 ? 0.0f : fQ;
            const int dKs = K - Ks;
            const int dKh = K - Kh;

            // neighbor boundary values rescaled into frame K (exact pow2)
            const float eLA = ldx(E7sA, dKs);   // left of row A; == diag of row B
            const float eLB = ldx(E7sB, dKs);
            const float eLC = ldx(E7sC, dKs);
            const float eLD = ldx(E7sD, dKs);
            float eDA0 = ldx(E7hD, dKh);        // diag of row A
            eDA0 = is0 ? 0.0f : eDA0;
            eDA0 = origin ? 1.0f : eDA0;

            const int i0 = t << 2;
            float QA[8];
            QA[0] = eDA0 + fq * Ep[0];
            #pragma unroll
            for (int c = 1; c < 8; ++c) QA[c] = fq * (Ep[c - 1] + Ep[c]);
            float EA[8];
            rowfma(endA, eLA, QA, EA);

            float QB[8];
            QB[0] = eLA + EA[0];
            #pragma unroll
            for (int c = 1; c < 8; ++c) QB[c] = EA[c - 1] + EA[c];
            float EB[8];
            rowfma(endB, eLB, QB, EB);

            float QC[8];
            QC[0] = eLB + EB[0];
            #pragma unroll
            for (int c = 1; c < 8; ++c) QC[c] = EB[c - 1] + EB[c];
            float EC[8];
            rowfma(endC, eLC, QC, EC);

            float QD[8];
            QD[0] = eLC + EC[0];
            #pragma unroll
            for (int c = 1; c < 8; ++c) QD[c] = EC[c - 1] + EC[c];
            float ED[8];
            rowfma(endD, eLD, QD, ED);

            // store E rows (post-pass converts) + frame g = K*ln2
            float4* rA = (float4*)(Rb + (size_t)(i0 + 0) * M_DIM + c0);
            rA[0] = make_float4(EA[0], EA[1], EA[2], EA[3]);
            rA[1] = make_float4(EA[4], EA[5], EA[6], EA[7]);
            float4* rB = (float4*)(Rb + (size_t)(i0 + 1) * M_DIM + c0);
            rB[0] = make_float4(EB[0], EB[1], EB[2], EB[3]);
            rB[1] = make_float4(EB[4], EB[5], EB[6], EB[7]);
            float4* rC = (float4*)(Rb + (size_t)(i0 + 2) * M_DIM + c0);
            rC[0] = make_float4(EC[0], EC[1], EC[2], EC[3]);
            rC[1] = make_float4(EC[4], EC[5], EC[6], EC[7]);
            float4* rD = (float4*)(Rb + (size_t)(i0 + 3) * M_DIM + c0);
            rD[0] = make_float4(ED[0], ED[1], ED[2], ED[3]);
            rD[1] = make_float4(ED[4], ED[5], ED[6], ED[7]);
            gm[(t << 6) + l] = (float)K * LN2F;

            // frame update: exact pow2 rescale for next quad
            const int ed = fr_exp(ED[0]);       // ED[0] = m * 2^ed, m in [0.5,1)
            KG = K - ed;
            fQ = ldx(1.0f, -ed);
            KE = K;
            #pragma unroll
            for (int c = 0; c < 8; ++c) Ep[c] = ED[c];
            expA7 = EA[7]; expB7 = EB[7]; expC7 = EC[7]; expD7 = ED[7];
        }

        // history update (all lanes)
        E7hD = E7sD;
        Kh   = Ks;

        // finalize next quad's ds_reads before they become 'cur' (rule 18)
        asm volatile("s_waitcnt lgkmcnt(0)" ::: "memory");
        __builtin_amdgcn_sched_barrier(0);
    };

    for (int s = 0; s < TSTEPS; s += 2) {
        step(s,     P,  Nx);
        step(s + 1, Nx, P);
    }
}

extern "C" void kernel_launch(void* const* d_in, const int* in_sizes, int n_in,
                              void* d_out, int out_size, void* d_ws, size_t ws_size,
                              hipStream_t stream) {
    const float* x = (const float*)d_in[0];
    float* out     = (float*)d_out;
    const int B    = in_sizes[0] / BSTRIDE;
    const int n4   = (B * BSTRIDE) / 4;
    const size_t DEXP_BYTES = (size_t)B * BSTRIDE * sizeof(float);
    const size_t GMAP_BYTES = (size_t)B * GSTRIDE * sizeof(float);

    if (ws_size >= DEXP_BYTES + GMAP_BYTES) {
        float* dexp = (float*)d_ws;
        float* gm   = (float*)((char*)d_ws + DEXP_BYTES);
        exp_pre<<<dim3(2048), dim3(256), 0, stream>>>((const float4*)x, (float4*)dexp, n4);
        softdtw_dp<true><<<dim3(B), dim3(64), 0, stream>>>(dexp, out, gm);
        log_post<<<dim3(2048), dim3(256), 0, stream>>>((float4*)out, gm, n4);
    } else {
        float* gm = (float*)d_ws;                    // needs only 1 MB
        softdtw_dp<false><<<dim3(B), dim3(64), 0, stream>>>(x, out, gm);
        log_post<<<dim3(2048), dim3(256), 0, stream>>>((float4*)out, gm, n4);
    }
}

// Round 10
// 135.454 us; speedup vs baseline: 2.3583x; 1.0144x over previous
//
#include <hip/hip_runtime.h>

#define N_DIM 512
#define M_DIM 512
#define NQUAD 128
#define TSTEPS 192          // even (ping-pong); 128 quads + 63 skew, padded
#define DEPTH 4
#define SLOT_BYTES 8192
#define RING_BYTES (DEPTH * SLOT_BYTES)
#define BSTRIDE (N_DIM * M_DIM)
#define GSTRIDE (NQUAD * 64)
#define ROW_BYTES 2048
#define ROW_MAX (511 * 2048)
#define LN2F 0.6931471805599453f

#define AS1 __attribute__((address_space(1)))
#define AS3 __attribute__((address_space(3)))

// -------- pass 1: Dexp = exp(-D), all CUs, memory-bound --------
__global__ __launch_bounds__(256) void exp_pre(const float4* __restrict__ D4,
                                               float4* __restrict__ E4, int n4) {
    int i = blockIdx.x * blockDim.x + threadIdx.x;
    const int stride = gridDim.x * blockDim.x;
    for (; i < n4; i += stride) {
        const float4 v = D4[i];
        E4[i] = make_float4(__expf(-v.x), __expf(-v.y), __expf(-v.z), __expf(-v.w));
    }
}

// -------- pass 3: R = g - log(E), in place on d_out --------
__global__ __launch_bounds__(256) void log_post(float4* __restrict__ E4,
                                                const float* __restrict__ gm, int n4) {
    int i = blockIdx.x * blockDim.x + threadIdx.x;
    const int stride = gridDim.x * blockDim.x;
    for (; i < n4; i += stride) {
        const int b   = i >> 16;            // 65536 float4 per batch
        const int rem = i & 65535;
        const int row = rem >> 7;           // 128 float4 per row
        const int c4  = rem & 127;
        const float g = gm[(b << 13) + ((row >> 2) << 6) + (c4 >> 1)];
        const float4 v = E4[i];
        E4[i] = make_float4(g - __logf(v.x), g - __logf(v.y),
                            g - __logf(v.z), g - __logf(v.w));
    }
}

// DPP wave-shift-right-by-1: lane i gets lane i-1's value, lane 0 gets 0.
__device__ inline float shup1(float x) {
    int r = __builtin_amdgcn_update_dpp(0, __float_as_int(x), 0x138, 0xf, 0xf, true);
    return __int_as_float(r);
}
__device__ inline int shup1i(int x) {
    return __builtin_amdgcn_update_dpp(0, x, 0x138, 0xf, 0xf, true);
}
__device__ inline int fr_exp(float x) {
    int e; asm("v_frexp_exp_i32_f32 %0, %1" : "=v"(e) : "v"(x)); return e;
}
__device__ inline float ldx(float x, int k) {
    float r; asm("v_ldexp_f32 %0, %1, %2" : "=v"(r) : "v"(x), "v"(k)); return r;
}

// -------- pass 2: exp-domain banded DP wave, integer pow2 frames --------
// Lane l owns columns [8l,8l+8); step s computes row-quad t = s-l.
// Stored E[j] = exp(-R[i][j]) * 2^K; R = K*ln2 - ln(E). Zero transcendentals
// in steady state; addressing via incremental 32-bit byte offsets.
// NOTE: global_load_lds is used ONLY with offset=0 (the validated form);
// the second 16B chunk's global address is an explicit +16B add.
template<bool PRE>
__global__ __launch_bounds__(64, 1) void softdtw_dp(const float* __restrict__ Dsrc,
                                                    float* __restrict__ Eout,
                                                    float* __restrict__ gmap) {
    const int b     = blockIdx.x;
    const int l     = threadIdx.x;
    const int laneB = l << 5;            // byte offset of lane's 8-col block in a row

    const float* __restrict__ Db = Dsrc + (size_t)b * BSTRIDE;  // exp(-D) if PRE
    float*       __restrict__ Rb = Eout + (size_t)b * BSTRIDE;
    float*       __restrict__ gm = gmap + (size_t)b * GSTRIDE;

    __shared__ char ring[RING_BYTES] __attribute__((aligned(16)));
    const unsigned ring_base = (unsigned)(size_t)(AS3 char*)ring;

    auto EV = [&](float v) -> float { return PRE ? v : __expf(-v); };

    // persistent state
    float Ep[8];
    #pragma unroll
    for (int k = 0; k < 8; ++k) Ep[k] = 0.0f;
    float fQ = 0.0f;
    int   KG = 0;          // frame chosen for the upcoming quad
    int   KE = 0;          // frame of exported E7 values
    int   Kh = 0;          // history: neighbor's Ks one step ago
    float expA7 = 0.0f, expB7 = 0.0f, expC7 = 0.0f, expD7 = 0.0f;
    float E7hD = 0.0f;     // history: neighbor's expD7 one step ago

    // incremental byte offsets
    int raw[4];            // DMA row offsets for sigma = s + DEPTH (init sigma=4)
    #pragma unroll
    for (int k = 0; k < 4; ++k) raw[k] = (16 + k) * ROW_BYTES - (l << 13);
    int soff = -(l << 13); // store offset = t * 8192 at step s (t = s - l)

    float4 P[8], Nx[8];
    // prologue: quad 0 direct loads + fill ring slots 1..3
    #pragma unroll
    for (int row = 0; row < 4; ++row) {
        const int r = min(max(-4 * l + row, 0), N_DIM - 1);
        P[2 * row]     = *(const float4*)(Db + (size_t)r * M_DIM + (l << 3));
        P[2 * row + 1] = *(const float4*)(Db + (size_t)r * M_DIM + (l << 3) + 4);
    }
    #pragma unroll
    for (int sig = 1; sig < DEPTH; ++sig) {
        const unsigned wo = (unsigned)sig * SLOT_BYTES;
        #pragma unroll
        for (int k = 0; k < 4; ++k) {
            const int cl = min(max((4 * (sig - l) + k) * ROW_BYTES, 0), ROW_MAX);
            const char* gp = (const char*)Db + cl + laneB;
            __builtin_amdgcn_global_load_lds((const AS1 void*)gp,
                                             (AS3 void*)(ring + wo + (2 * k) * 1024), 16, 0, 0);
            __builtin_amdgcn_global_load_lds((const AS1 void*)(gp + 16),
                                             (AS3 void*)(ring + wo + (2 * k + 1) * 1024), 16, 0, 0);
        }
    }
    asm volatile("s_waitcnt vmcnt(0)" ::: "memory");

    auto rowfma = [&](const float* endv, float eLeft, const float* Q, float* E) {
        float e = eLeft;
        #pragma unroll
        for (int c = 0; c < 8; ++c) {
            e = __builtin_fmaf(endv[c], e, endv[c] * Q[c]);
            E[c] = e;
        }
    };

    auto step = [&](int s, float4 (&cur)[8], float4 (&nxt)[8]) {
        // (1) DMA quad for step s+DEPTH: incremental clamped offsets
        {
            const unsigned wo = ((unsigned)(s + DEPTH) & (DEPTH - 1)) * SLOT_BYTES;
            #pragma unroll
            for (int k = 0; k < 4; ++k) {
                const int cl = min(max(raw[k], 0), ROW_MAX);   // v_med3_i32
                const char* gp = (const char*)Db + cl + laneB;
                __builtin_amdgcn_global_load_lds((const AS1 void*)gp,
                                                 (AS3 void*)(ring + wo + (2 * k) * 1024), 16, 0, 0);
                __builtin_amdgcn_global_load_lds((const AS1 void*)(gp + 16),
                                                 (AS3 void*)(ring + wo + (2 * k + 1) * 1024), 16, 0, 0);
                raw[k] += 4 * ROW_BYTES;
            }
        }
        // (2) vmcnt bookkeeping (stores count too): ops newer than slot-(s+1)'s
        // DMA batch: st(s-3)9 + D(s+2)8 + st(s-2)9 + D(s+3)8 + st(s-1)9 + D(s+4)8 = 51
        asm volatile("s_waitcnt vmcnt(51)" ::: "memory");

        // (3) boundary from lane l-1 via DPP (lane 0 gets 0 = BIG boundary)
        const float E7sA = shup1(expA7);
        const float E7sB = shup1(expB7);
        const float E7sC = shup1(expC7);
        const float E7sD = shup1(expD7);
        const int   Ks   = shup1i(KE);

        // (4) issue ds_read of next step's quad (completes under compute)
        const unsigned raddr = ring_base
                             + (unsigned)((s + 1) & (DEPTH - 1)) * SLOT_BYTES
                             + (unsigned)l * 16u;
        asm volatile("ds_read_b128 %0, %8 offset:0\n\t"
                     "ds_read_b128 %1, %8 offset:1024\n\t"
                     "ds_read_b128 %2, %8 offset:2048\n\t"
                     "ds_read_b128 %3, %8 offset:3072\n\t"
                     "ds_read_b128 %4, %8 offset:4096\n\t"
                     "ds_read_b128 %5, %8 offset:5120\n\t"
                     "ds_read_b128 %6, %8 offset:6144\n\t"
                     "ds_read_b128 %7, %8 offset:7168"
                     : "=&v"(nxt[0]), "=&v"(nxt[1]), "=&v"(nxt[2]), "=&v"(nxt[3]),
                       "=&v"(nxt[4]), "=&v"(nxt[5]), "=&v"(nxt[6]), "=&v"(nxt[7])
                     : "v"(raddr));

        // (5) compute quad t = s - l
        const int t = s - l;
        if (t >= 0 && t < NQUAD) {
            const float endA[8] = {EV(cur[0].x), EV(cur[0].y), EV(cur[0].z), EV(cur[0].w),
                                   EV(cur[1].x), EV(cur[1].y), EV(cur[1].z), EV(cur[1].w)};
            const float endB[8] = {EV(cur[2].x), EV(cur[2].y), EV(cur[2].z), EV(cur[2].w),
                                   EV(cur[3].x), EV(cur[3].y), EV(cur[3].z), EV(cur[3].w)};
            const float endC[8] = {EV(cur[4].x), EV(cur[4].y), EV(cur[4].z), EV(cur[4].w),
                                   EV(cur[5].x), EV(cur[5].y), EV(cur[5].z), EV(cur[5].w)};
            const float endD[8] = {EV(cur[6].x), EV(cur[6].y), EV(cur[6].z), EV(cur[6].w),
                                   EV(cur[7].x), EV(cur[7].y), EV(cur[7].z), EV(cur[7].w)};

            // frame selection (branch-free adoption at t==0)
            const bool is0    = (t == 0);
            const bool origin = is0 && (l == 0);
            int K = is0 ? (Ks - fr_exp(E7sA)) : KG;
            K = origin ? 0 : K;
            const float fq = is0 ? 0.0f : fQ;
            const int dKs = K - Ks;
            const int dKh = K - Kh;

            // neighbor boundary values rescaled into frame K (exact pow2)
            const float eLA = ldx(E7sA, dKs);   // left of row A; == diag of row B
            const float eLB = ldx(E7sB, dKs);
            const float eLC = ldx(E7sC, dKs);
            const float eLD = ldx(E7sD, dKs);
            float eDA0 = ldx(E7hD, dKh);        // diag of row A
            eDA0 = is0 ? 0.0f : eDA0;
            eDA0 = origin ? 1.0f : eDA0;

            float QA[8];
            QA[0] = eDA0 + fq * Ep[0];
            #pragma unroll
            for (int c = 1; c < 8; ++c) QA[c] = fq * (Ep[c - 1] + Ep[c]);
            float EA[8];
            rowfma(endA, eLA, QA, EA);

            float QB[8];
            QB[0] = eLA + EA[0];
            #pragma unroll
            for (int c = 1; c < 8; ++c) QB[c] = EA[c - 1] + EA[c];
            float EB[8];
            rowfma(endB, eLB, QB, EB);

            float QC[8];
            QC[0] = eLB + EB[0];
            #pragma unroll
            for (int c = 1; c < 8; ++c) QC[c] = EB[c - 1] + EB[c];
            float EC[8];
            rowfma(endC, eLC, QC, EC);

            float QD[8];
            QD[0] = eLC + EC[0];
            #pragma unroll
            for (int c = 1; c < 8; ++c) QD[c] = EC[c - 1] + EC[c];
            float ED[8];
            rowfma(endD, eLD, QD, ED);

            // store E rows: one running base + immediate offsets
            char* sb  = (char*)Rb + soff + laneB;
            char* sb2 = sb + 4096;
            *(float4*)(sb)         = make_float4(EA[0], EA[1], EA[2], EA[3]);
            *(float4*)(sb + 16)    = make_float4(EA[4], EA[5], EA[6], EA[7]);
            *(float4*)(sb + 2048)  = make_float4(EB[0], EB[1], EB[2], EB[3]);
            *(float4*)(sb + 2064)  = make_float4(EB[4], EB[5], EB[6], EB[7]);
            *(float4*)(sb2)        = make_float4(EC[0], EC[1], EC[2], EC[3]);
            *(float4*)(sb2 + 16)   = make_float4(EC[4], EC[5], EC[6], EC[7]);
            *(float4*)(sb2 + 2048) = make_float4(ED[0], ED[1], ED[2], ED[3]);
            *(float4*)(sb2 + 2064) = make_float4(ED[4], ED[5], ED[6], ED[7]);
            gm[(t << 6) + l] = (float)K * LN2F;

            // frame update: exact pow2 rescale for next quad
            const int ed = fr_exp(ED[0]);       // ED[0] = m * 2^ed
            KG = K - ed;
            fQ = ldx(1.0f, -ed);
            KE = K;
            #pragma unroll
            for (int c = 0; c < 8; ++c) Ep[c] = ED[c];
            expA7 = EA[7]; expB7 = EB[7]; expC7 = EC[7]; expD7 = ED[7];
        }

        // (6) history + offset update (all lanes)
        E7hD = E7sD;
        Kh   = Ks;
        soff += 4 * ROW_BYTES;

        // (7) finalize next quad's ds_reads before they become 'cur' (rule 18)
        asm volatile("s_waitcnt lgkmcnt(0)" ::: "memory");
        __builtin_amdgcn_sched_barrier(0);
    };

    for (int s = 0; s < TSTEPS; s += 2) {
        step(s,     P,  Nx);
        step(s + 1, Nx, P);
    }
}

extern "C" void kernel_launch(void* const* d_in, const int* in_sizes, int n_in,
                              void* d_out, int out_size, void* d_ws, size_t ws_size,
                              hipStream_t stream) {
    const float* x = (const float*)d_in[0];
    float* out     = (float*)d_out;
    const int B    = in_sizes[0] / BSTRIDE;
    const int n4   = (B * BSTRIDE) / 4;
    const size_t DEXP_BYTES = (size_t)B * BSTRIDE * sizeof(float);
    const size_t GMAP_BYTES = (size_t)B * GSTRIDE * sizeof(float);

    if (ws_size >= DEXP_BYTES + GMAP_BYTES) {
        float* dexp = (float*)d_ws;
        float* gm   = (float*)((char*)d_ws + DEXP_BYTES);
        exp_pre<<<dim3(2048), dim3(256), 0, stream>>>((const float4*)x, (float4*)dexp, n4);
        softdtw_dp<true><<<dim3(B), dim3(64), 0, stream>>>(dexp, out, gm);
        log_post<<<dim3(2048), dim3(256), 0, stream>>>((float4*)out, gm, n4);
    } else {
        float* gm = (float*)d_ws;                    // needs only 1 MB
        softdtw_dp<false><<<dim3(B), dim3(64), 0, stream>>>(x, out, gm);
        log_post<<<dim3(2048), dim3(256), 0, stream>>>((float4*)out, gm, n4);
    }
}